// Round 11
// baseline (1056.357 us; speedup 1.0000x reference)
//
#include <hip/hip_runtime.h>
#include <cstdint>
#include <cstddef>

#define TDIM 4096
#define HDIM 2048
#define FDIM 1408
#define NEXP 8
#define NSLOT (TDIM * 2)
#define BK 32

typedef _Float16 half8 __attribute__((ext_vector_type(8)));
typedef _Float16 half4 __attribute__((ext_vector_type(4)));
typedef float floatx4 __attribute__((ext_vector_type(4)));

#define AS1 __attribute__((address_space(1)))
#define AS3 __attribute__((address_space(3)))

// async global->LDS, 16B per lane; lds dst is wave-uniform base (+lane*16B scatter)
__device__ __forceinline__ void g2l16(const _Float16* g, _Float16* l) {
  __builtin_amdgcn_global_load_lds((const AS1 unsigned*)g, (AS3 unsigned*)l, 16, 0, 0);
}

// compiler-level memory fence (zero instructions): keeps LDS reads / stage ops
// from being scheduled across a raw s_barrier by the compiler
#define CFENCE() asm volatile("" ::: "memory")

// ---------------- ws layout (bytes) ----------------
static constexpr size_t ws_align(size_t x) { return (x + 511) & ~(size_t)511; }
static constexpr size_t WS_XB     = 0;                                  // f16 [TDIM][HDIM]
static constexpr size_t WS_ACT_S  = WS_XB    + (size_t)TDIM * HDIM * 2; // f16 [TDIM][FDIM]
static constexpr size_t WS_ACT_R  = WS_ACT_S + (size_t)TDIM * FDIM * 2; // f16 [NSLOT][FDIM]
static constexpr size_t WS_TOKE   = WS_ACT_R + (size_t)NSLOT * FDIM * 2;// int  [TDIM][2]
static constexpr size_t WS_TOKG   = WS_TOKE  + (size_t)TDIM * 2 * 4;    // f32  [TDIM][2]
static constexpr size_t WS_SLOTT  = WS_TOKG  + (size_t)TDIM * 2 * 4;    // int  [NSLOT]
static constexpr size_t WS_SLOTG  = WS_SLOTT + (size_t)NSLOT * 4;       // f32  [NSLOT]
static constexpr size_t WS_COUNTS = WS_SLOTG + (size_t)NSLOT * 4;       // int  [NEXP] (64B slot)
static constexpr size_t WS_FILL   = WS_COUNTS + 64;                     // int  [NEXP] (64B slot)
static constexpr size_t WS_OFFS   = WS_FILL   + 64;                     // int  [NEXP]
static constexpr size_t WS_WS1H   = ws_align(WS_OFFS + 64);
static constexpr size_t WS_WS3H   = WS_WS1H + (size_t)FDIM * HDIM * 2;
static constexpr size_t WS_WS2H   = WS_WS3H + (size_t)FDIM * HDIM * 2;
static constexpr size_t WS_WE1H   = WS_WS2H + (size_t)HDIM * FDIM * 2;
static constexpr size_t WS_WE3H   = WS_WE1H + (size_t)NEXP * FDIM * HDIM * 2;
static constexpr size_t WS_WE2H   = WS_WE3H + (size_t)NEXP * FDIM * HDIM * 2;
static constexpr size_t WS_END    = WS_WE2H + (size_t)NEXP * HDIM * FDIM * 2;

// ---------------- small kernels ----------------

__global__ void zero_meta_kernel(int* __restrict__ counts) {
  if (threadIdx.x < 32) counts[threadIdx.x] = 0;
}

// fp32 -> f16 for 3 equal-size tensors (blockIdx.y selects), 8 elems/thread
__global__ void cvt3_kernel(const float* __restrict__ s0, const float* __restrict__ s1,
                            const float* __restrict__ s2, _Float16* __restrict__ d0,
                            _Float16* __restrict__ d1, _Float16* __restrict__ d2) {
  const float* s;
  _Float16* d;
  if (blockIdx.y == 0)      { s = s0; d = d0; }
  else if (blockIdx.y == 1) { s = s1; d = d1; }
  else                      { s = s2; d = d2; }
  size_t i = ((size_t)blockIdx.x * 256 + threadIdx.x) * 8;
  float4 a = *(const float4*)(s + i);
  float4 b = *(const float4*)(s + i + 4);
  half8 h;
  h[0] = (_Float16)a.x; h[1] = (_Float16)a.y; h[2] = (_Float16)a.z; h[3] = (_Float16)a.w;
  h[4] = (_Float16)b.x; h[5] = (_Float16)b.y; h[6] = (_Float16)b.z; h[7] = (_Float16)b.w;
  *(half8*)(d + i) = h;
}

// one wave per token: fp32 routing (discrete decisions must match reference).
// Also emits the f16 copy of x (row is already in registers) -> saves a cvt pass.
__global__ void gate_kernel(const float* __restrict__ x, const float* __restrict__ gw,
                            const float* __restrict__ bias, _Float16* __restrict__ xb,
                            int* __restrict__ toke, float* __restrict__ tokg,
                            int* __restrict__ counts) {
  const int wid  = blockIdx.x * 4 + (threadIdx.x >> 6);
  const int lane = threadIdx.x & 63;
  const float4* xv = (const float4*)(x + (size_t)wid * HDIM);
  const float4* gv = (const float4*)gw;
  _Float16* xrow = xb + (size_t)wid * HDIM;
  float acc[NEXP];
#pragma unroll
  for (int e = 0; e < NEXP; ++e) acc[e] = 0.f;
#pragma unroll
  for (int i = 0; i < 8; ++i) {
    float4 xq = xv[lane + 64 * i];
    half4 hq;
    hq[0] = (_Float16)xq.x; hq[1] = (_Float16)xq.y;
    hq[2] = (_Float16)xq.z; hq[3] = (_Float16)xq.w;
    *(half4*)(xrow + 4 * (lane + 64 * i)) = hq;
#pragma unroll
    for (int e = 0; e < NEXP; ++e) {
      float4 gq = gv[e * 512 + lane + 64 * i];
      acc[e] += xq.x * gq.x + xq.y * gq.y + xq.z * gq.z + xq.w * gq.w;
    }
  }
#pragma unroll
  for (int e = 0; e < NEXP; ++e) {
    float v = acc[e];
    for (int off = 32; off; off >>= 1) v += __shfl_xor(v, off);
    acc[e] = v;
  }
  if (lane == 0) {
    float s[NEXP], r[NEXP];
#pragma unroll
    for (int e = 0; e < NEXP; ++e) {
      s[e] = 1.f / (1.f + __expf(-acc[e]));
      r[e] = s[e] + bias[e];
    }
    int e0 = 0;
#pragma unroll
    for (int e = 1; e < NEXP; ++e) if (r[e] > r[e0]) e0 = e;
    int e1 = -1;
#pragma unroll
    for (int e = 0; e < NEXP; ++e) if (e != e0 && (e1 < 0 || r[e] > r[e1])) e1 = e;
    float g0 = s[e0], g1 = s[e1];
    float inv = 1.f / (g0 + g1);
    toke[wid * 2]     = e0;
    toke[wid * 2 + 1] = e1;
    tokg[wid * 2]     = g0 * inv;
    tokg[wid * 2 + 1] = g1 * inv;
    atomicAdd(&counts[e0], 1);
    atomicAdd(&counts[e1], 1);
  }
}

__global__ void offsets_kernel(const int* __restrict__ counts, int* __restrict__ offs) {
  if (threadIdx.x == 0) {
    int o = 0;
    for (int e = 0; e < NEXP; ++e) { offs[e] = o; o += counts[e]; }
  }
}

__global__ void scatter_kernel(const int* __restrict__ toke, const float* __restrict__ tokg,
                               const int* __restrict__ offs, int* __restrict__ fill,
                               int* __restrict__ slott, float* __restrict__ slotg) {
  int t = blockIdx.x * 256 + threadIdx.x;
#pragma unroll
  for (int j = 0; j < 2; ++j) {
    int e = toke[t * 2 + j];
    float g = tokg[t * 2 + j];
    int p = offs[e] + atomicAdd(&fill[e], 1);
    slott[p] = t;
    slotg[p] = g;
  }
}

// ---------------- GEMM kernels ----------------
// 128x128 tile, BK=32, TRIPLE-buffered LDS, 256 thr (4 waves, 2x2 of 64x64),
// MFMA 16x16x32 f16.
// Schedule (counted-vmcnt, ONE barrier per K-step, R7 shape):
//   step t: stage(t+2 -> buf[(t+2)%3])            (top: overlaps compute)
//           ds_read buf[t%3] + MFMA
//           s_waitcnt vmcnt(N) lgkmcnt(0)          N = loads of ONE tile ->
//           s_barrier                              stage(t+1) landed, t+2 in flight
// 3 buffers make stage(t+2)'s target the buffer last READ at t-1, already
// protected by the end-of-(t-1) barrier -> no extra readers-done barrier
// (R8's mistake). Loads get ~1.5 steps to land instead of the __syncthreads
// vmcnt(0) drain at the end of the issuing step (the measured 19%-MfmaUtil
// limiter in R7/R9: per-step residual wait on 600-900cy weight loads).
// T1 XCD group-locality swizzle kept (FETCH -27% measured in R9).
// LDS chunk-XOR swizzle: LDS[row][c] = G[row][c ^ ((row>>1)&3)] at global src;
// readback chunk' = quad ^ ((lrow>>1)&3) -> conflict-free ds_read_b128.
// bz: 0 = shared expert (all tokens, dense), 1..8 = routed expert bz-1.

__global__ __launch_bounds__(256) void up_kernel(
    const _Float16* __restrict__ xb,
    const _Float16* __restrict__ ws1h, const _Float16* __restrict__ ws3h,
    const _Float16* __restrict__ we1h, const _Float16* __restrict__ we3h,
    _Float16* __restrict__ acts, _Float16* __restrict__ actr,
    const int* __restrict__ counts, const int* __restrict__ offs,
    const int* __restrict__ slott) {
  constexpr int GX = FDIM / 128;   // 11
  constexpr int GY = TDIM / 128;   // 32
  // bijective XCD group swizzle (all-SGPR)
  const int orig = blockIdx.x + GX * (blockIdx.y + GY * blockIdx.z);
  const int k8 = orig & 7, s = orig >> 3;
  const int g = k8 + 8 * (s / GX);
  const int lid = g * GX + (s % GX);
  const int bx = lid % GX;
  const int by = (lid / GX) % GY;
  const int bz = lid / (GX * GY);

  int cnt = TDIM, base = 0;
  const _Float16* __restrict__ W1 = ws1h;
  const _Float16* __restrict__ W3 = ws3h;
  _Float16* __restrict__ act = acts;
  bool gather = false;
  if (bz > 0) {
    const int e = bz - 1;
    cnt = counts[e];
    base = offs[e];
    if ((int)(by * 128) >= cnt) return;
    W1 = we1h + (size_t)e * FDIM * HDIM;
    W3 = we3h + (size_t)e * FDIM * HDIM;
    act = actr;
    gather = true;
  }
  const int m0 = by * 128, n0 = bx * 128;

  __shared__ _Float16 As[3][128 * BK];
  __shared__ _Float16 B1s[3][128 * BK];
  __shared__ _Float16 B3s[3][128 * BK];

  const int tid = threadIdx.x, lane = tid & 63, wv = tid >> 6;
  const int wm = wv >> 1, wn = wv & 1;
  const int lrow = lane & 15, quad = lane >> 4;

  // staging: wave wv call j covers tile rows wv*32+j*16 .. +16 (1KB each)
  const _Float16 *srcA[2], *srcB1[2], *srcB3[2];
  int lb_[2];
#pragma unroll
  for (int j = 0; j < 2; ++j) {
    const int rr = wv * 32 + j * 16 + (lane >> 2);
    const int gc = ((lane & 3) ^ ((rr >> 1) & 3)) * 8;  // pre-swizzled source chunk
    const int m = m0 + rr;
    int tok;
    if (gather) tok = slott[base + (m < cnt ? m : cnt - 1)];
    else tok = m;
    srcA[j]  = xb + (size_t)tok * HDIM + gc;
    srcB1[j] = W1 + (size_t)(n0 + rr) * HDIM + gc;
    srcB3[j] = W3 + (size_t)(n0 + rr) * HDIM + gc;
    lb_[j] = (wv * 32 + j * 16) * BK;
  }

  // 6 g2l16 per wave per tile -> steady-state wait is vmcnt(6)
  auto stage = [&](int tt, int b) {
    const int k0 = tt * BK;
#pragma unroll
    for (int j = 0; j < 2; ++j) {
      g2l16(srcA[j] + k0,  &As[b][lb_[j]]);
      g2l16(srcB1[j] + k0, &B1s[b][lb_[j]]);
      g2l16(srcB3[j] + k0, &B3s[b][lb_[j]]);
    }
  };

  floatx4 acc1[4][4] = {};
  floatx4 acc3[4][4] = {};
  const int cA = (quad ^ ((lrow >> 1) & 3)) * 8;  // swizzled read chunk (halfs)

  constexpr int NT = HDIM / BK;  // 64
  // prologue: 2-deep prefetch
  stage(0, 0);
  stage(1, 1);
  asm volatile("s_waitcnt vmcnt(6)" ::: "memory");  // own stage(0) landed
  CFENCE(); __builtin_amdgcn_s_barrier(); CFENCE(); // all waves' stage(0) landed

  int cur = 0;
  for (int t = 0; t < NT; ++t) {
    if (t + 2 < NT) {                  // stage 2 ahead into buffer read at t-1
      int b2 = cur + 2; if (b2 >= 3) b2 -= 3;
      stage(t + 2, b2);
    }
    half8 af[4], b1f[4], b3f[4];
#pragma unroll
    for (int i = 0; i < 4; ++i)
      af[i] = *(const half8*)&As[cur][(wm * 64 + i * 16 + lrow) * BK + cA];
#pragma unroll
    for (int i = 0; i < 4; ++i) {
      b1f[i] = *(const half8*)&B1s[cur][(wn * 64 + i * 16 + lrow) * BK + cA];
      b3f[i] = *(const half8*)&B3s[cur][(wn * 64 + i * 16 + lrow) * BK + cA];
    }
#pragma unroll
    for (int ms = 0; ms < 4; ++ms)
#pragma unroll
      for (int ns = 0; ns < 4; ++ns) {
        acc1[ms][ns] = __builtin_amdgcn_mfma_f32_16x16x32_f16(af[ms], b1f[ns], acc1[ms][ns], 0, 0, 0);
        acc3[ms][ns] = __builtin_amdgcn_mfma_f32_16x16x32_f16(af[ms], b3f[ns], acc3[ms][ns], 0, 0, 0);
      }
    // stage(t+1) landed (vmcnt: 12 outstanding -> 6); all our ds_reads returned
    if (t + 2 < NT) asm volatile("s_waitcnt vmcnt(6) lgkmcnt(0)" ::: "memory");
    else            asm volatile("s_waitcnt vmcnt(0) lgkmcnt(0)" ::: "memory");
    CFENCE(); __builtin_amdgcn_s_barrier(); CFENCE();
    cur = (cur == 2) ? 0 : cur + 1;
  }

  // epilogue: silu(h1)*h3 (C/D layout: col=lane&15, row=quad*4+reg)
#pragma unroll
  for (int ms = 0; ms < 4; ++ms)
#pragma unroll
    for (int ns = 0; ns < 4; ++ns)
#pragma unroll
      for (int r = 0; r < 4; ++r) {
        float h1 = acc1[ms][ns][r];
        float h3 = acc3[ms][ns][r];
        float a = h1 / (1.f + __expf(-h1)) * h3;
        const int rl = wm * 64 + ms * 16 + quad * 4 + r;
        const int f = n0 + wn * 64 + ns * 16 + lrow;
        const int m = m0 + rl;
        if (gather) {
          if (m < cnt) act[(size_t)(base + m) * FDIM + f] = (_Float16)a;
        } else {
          act[(size_t)m * FDIM + f] = (_Float16)a;
        }
      }
}

// down: A (f16 act) @ W2^T; out pre-zeroed, all paths atomicAdd (order-free)
__global__ __launch_bounds__(256) void down_kernel(
    const _Float16* __restrict__ acts, const _Float16* __restrict__ actr,
    const _Float16* __restrict__ ws2h, const _Float16* __restrict__ we2h,
    float* __restrict__ out,
    const int* __restrict__ counts, const int* __restrict__ offs,
    const int* __restrict__ slott, const float* __restrict__ slotg) {
  constexpr int GX = HDIM / 128;   // 16
  constexpr int GY = TDIM / 128;   // 32
  const int orig = blockIdx.x + GX * (blockIdx.y + GY * blockIdx.z);
  const int k8 = orig & 7, s = orig >> 3;
  const int g = k8 + 8 * (s / GX);
  const int lid = g * GX + (s % GX);
  const int bx = lid % GX;
  const int by = (lid / GX) % GY;
  const int bz = lid / (GX * GY);

  int cnt = TDIM, base = 0;
  const _Float16* __restrict__ A = acts;
  const _Float16* __restrict__ W = ws2h;
  bool gather = false;
  if (bz > 0) {
    const int e = bz - 1;
    cnt = counts[e];
    base = offs[e];
    if ((int)(by * 128) >= cnt) return;
    A = actr;
    W = we2h + (size_t)e * HDIM * FDIM;
    gather = true;
  }
  const int m0 = by * 128, n0 = bx * 128;

  __shared__ _Float16 As[3][128 * BK];
  __shared__ _Float16 Bs[3][128 * BK];

  const int tid = threadIdx.x, lane = tid & 63, wv = tid >> 6;
  const int wm = wv >> 1, wn = wv & 1;
  const int lrow = lane & 15, quad = lane >> 4;

  const _Float16 *srcA[2], *srcB[2];
  int lb_[2];
#pragma unroll
  for (int j = 0; j < 2; ++j) {
    const int rr = wv * 32 + j * 16 + (lane >> 2);
    const int gc = ((lane & 3) ^ ((rr >> 1) & 3)) * 8;
    const int m = m0 + rr;
    int srow;
    if (gather) srow = base + (m < cnt ? m : cnt - 1);
    else srow = m;
    srcA[j] = A + (size_t)srow * FDIM + gc;
    srcB[j] = W + (size_t)(n0 + rr) * FDIM + gc;
    lb_[j] = (wv * 32 + j * 16) * BK;
  }

  // 4 g2l16 per wave per tile -> steady-state wait is vmcnt(4)
  auto stage = [&](int tt, int b) {
    const int k0 = tt * BK;
#pragma unroll
    for (int j = 0; j < 2; ++j) {
      g2l16(srcA[j] + k0, &As[b][lb_[j]]);
      g2l16(srcB[j] + k0, &Bs[b][lb_[j]]);
    }
  };

  floatx4 acc[4][4] = {};
  const int cA = (quad ^ ((lrow >> 1) & 3)) * 8;

  constexpr int NT = FDIM / BK;  // 44
  stage(0, 0);
  stage(1, 1);
  asm volatile("s_waitcnt vmcnt(4)" ::: "memory");
  CFENCE(); __builtin_amdgcn_s_barrier(); CFENCE();

  int cur = 0;
  for (int t = 0; t < NT; ++t) {
    if (t + 2 < NT) {
      int b2 = cur + 2; if (b2 >= 3) b2 -= 3;
      stage(t + 2, b2);
    }
    half8 af[4], bf[4];
#pragma unroll
    for (int i = 0; i < 4; ++i)
      af[i] = *(const half8*)&As[cur][(wm * 64 + i * 16 + lrow) * BK + cA];
#pragma unroll
    for (int i = 0; i < 4; ++i)
      bf[i] = *(const half8*)&Bs[cur][(wn * 64 + i * 16 + lrow) * BK + cA];
#pragma unroll
    for (int ms = 0; ms < 4; ++ms)
#pragma unroll
      for (int ns = 0; ns < 4; ++ns)
        acc[ms][ns] = __builtin_amdgcn_mfma_f32_16x16x32_f16(af[ms], bf[ns], acc[ms][ns], 0, 0, 0);
    if (t + 2 < NT) asm volatile("s_waitcnt vmcnt(4) lgkmcnt(0)" ::: "memory");
    else            asm volatile("s_waitcnt vmcnt(0) lgkmcnt(0)" ::: "memory");
    CFENCE(); __builtin_amdgcn_s_barrier(); CFENCE();
    cur = (cur == 2) ? 0 : cur + 1;
  }

#pragma unroll
  for (int ms = 0; ms < 4; ++ms)
#pragma unroll
    for (int ns = 0; ns < 4; ++ns)
#pragma unroll
      for (int r = 0; r < 4; ++r) {
        float v = acc[ms][ns][r];
        const int rl = wm * 64 + ms * 16 + quad * 4 + r;
        const int h = n0 + wn * 64 + ns * 16 + lrow;
        const int m = m0 + rl;
        if (gather) {
          if (m < cnt) {
            const int sl = base + m;
            atomicAdd(&out[(size_t)slott[sl] * HDIM + h], v * slotg[sl]);
          }
        } else {
          atomicAdd(&out[(size_t)m * HDIM + h], v);
        }
      }
}

// ---------------- launcher ----------------

extern "C" void kernel_launch(void* const* d_in, const int* in_sizes, int n_in,
                              void* d_out, int out_size, void* d_ws, size_t ws_size,
                              hipStream_t stream) {
  const float* x    = (const float*)d_in[0];
  const float* gw   = (const float*)d_in[1];
  const float* bias = (const float*)d_in[2];
  const float* ws1  = (const float*)d_in[3];
  const float* ws2  = (const float*)d_in[4];
  const float* ws3  = (const float*)d_in[5];
  const float* we1  = (const float*)d_in[6];
  const float* we2  = (const float*)d_in[7];
  const float* we3  = (const float*)d_in[8];
  float* out = (float*)d_out;

  char* ws = (char*)d_ws;
  _Float16* xb   = (_Float16*)(ws + WS_XB);
  _Float16* acts = (_Float16*)(ws + WS_ACT_S);
  _Float16* actr = (_Float16*)(ws + WS_ACT_R);
  int*   toke  = (int*)(ws + WS_TOKE);
  float* tokg  = (float*)(ws + WS_TOKG);
  int*   slott = (int*)(ws + WS_SLOTT);
  float* slotg = (float*)(ws + WS_SLOTG);
  int* counts  = (int*)(ws + WS_COUNTS);
  int* fill    = (int*)(ws + WS_FILL);
  int* offs    = (int*)(ws + WS_OFFS);
  _Float16* ws1h = (_Float16*)(ws + WS_WS1H);
  _Float16* ws3h = (_Float16*)(ws + WS_WS3H);
  _Float16* ws2h = (_Float16*)(ws + WS_WS2H);
  _Float16* we1h = (_Float16*)(ws + WS_WE1H);
  _Float16* we3h = (_Float16*)(ws + WS_WE3H);
  _Float16* we2h = (_Float16*)(ws + WS_WE2H);

  hipLaunchKernelGGL(zero_meta_kernel, dim3(1), dim3(64), 0, stream, counts);
  hipLaunchKernelGGL(gate_kernel, dim3(1024), dim3(256), 0, stream, x, gw, bias, xb, toke, tokg, counts);
  hipLaunchKernelGGL(offsets_kernel, dim3(1), dim3(64), 0, stream, counts, offs);
  hipLaunchKernelGGL(scatter_kernel, dim3(16), dim3(256), 0, stream, toke, tokg, offs, fill, slott, slotg);

  constexpr int GS = (FDIM * HDIM) / 2048;           // 1408
  constexpr int GR = (NEXP * FDIM * HDIM) / 2048;    // 11264
  hipLaunchKernelGGL(cvt3_kernel, dim3(GS, 3), dim3(256), 0, stream, ws1, ws3, ws2, ws1h, ws3h, ws2h);
  hipLaunchKernelGGL(cvt3_kernel, dim3(GR, 3), dim3(256), 0, stream, we1, we3, we2, we1h, we3h, we2h);

  hipMemsetAsync(out, 0, (size_t)TDIM * HDIM * sizeof(float), stream);

  // z = 0: shared expert (dense over all tokens); z = 1..8: routed expert z-1
  hipLaunchKernelGGL(up_kernel, dim3(FDIM / 128, TDIM / 128, NEXP + 1), dim3(256), 0, stream,
                     xb, ws1h, ws3h, we1h, we3h, acts, actr, counts, offs, slott);
  hipLaunchKernelGGL(down_kernel, dim3(HDIM / 128, TDIM / 128, NEXP + 1), dim3(256), 0, stream,
                     acts, actr, ws2h, we2h, out, counts, offs, slott, slotg);
}

// Round 12
// 912.815 us; speedup vs baseline: 1.1573x; 1.1573x over previous
//
#include <hip/hip_runtime.h>
#include <cstdint>
#include <cstddef>

#define TDIM 4096
#define HDIM 2048
#define FDIM 1408
#define NEXP 8
#define NSLOT (TDIM * 2)
#define BK 32

typedef _Float16 half8 __attribute__((ext_vector_type(8)));
typedef _Float16 half4 __attribute__((ext_vector_type(4)));
typedef float floatx4 __attribute__((ext_vector_type(4)));

#define AS1 __attribute__((address_space(1)))
#define AS3 __attribute__((address_space(3)))

// async global->LDS, 16B per lane; lds dst is wave-uniform base (+lane*16B scatter)
__device__ __forceinline__ void g2l16(const _Float16* g, _Float16* l) {
  __builtin_amdgcn_global_load_lds((const AS1 unsigned*)g, (AS3 unsigned*)l, 16, 0, 0);
}

// ---------------- ws layout (bytes) ----------------
static constexpr size_t ws_align(size_t x) { return (x + 511) & ~(size_t)511; }
static constexpr size_t WS_XB     = 0;                                  // f16 [TDIM][HDIM]
static constexpr size_t WS_ACT_S  = WS_XB    + (size_t)TDIM * HDIM * 2; // f16 [TDIM][FDIM]
static constexpr size_t WS_ACT_R  = WS_ACT_S + (size_t)TDIM * FDIM * 2; // f16 [NSLOT][FDIM]
static constexpr size_t WS_TOKE   = WS_ACT_R + (size_t)NSLOT * FDIM * 2;// int  [TDIM][2]
static constexpr size_t WS_TOKG   = WS_TOKE  + (size_t)TDIM * 2 * 4;    // f32  [TDIM][2]
static constexpr size_t WS_SLOTT  = WS_TOKG  + (size_t)TDIM * 2 * 4;    // int  [NSLOT]
static constexpr size_t WS_SLOTG  = WS_SLOTT + (size_t)NSLOT * 4;       // f32  [NSLOT]
static constexpr size_t WS_TOKS   = WS_SLOTG + (size_t)NSLOT * 4;       // int  [TDIM][2]
static constexpr size_t WS_COUNTS = WS_TOKS  + (size_t)TDIM * 2 * 4;    // int  [NEXP] (64B slot)
static constexpr size_t WS_FILL   = WS_COUNTS + 64;                     // int  [NEXP] (64B slot)
static constexpr size_t WS_OFFS   = WS_FILL   + 64;                     // int  [NEXP]
static constexpr size_t WS_WS1H   = ws_align(WS_OFFS + 64);
static constexpr size_t WS_WS3H   = WS_WS1H + (size_t)FDIM * HDIM * 2;
static constexpr size_t WS_WS2H   = WS_WS3H + (size_t)FDIM * HDIM * 2;
static constexpr size_t WS_WE1H   = WS_WS2H + (size_t)HDIM * FDIM * 2;
static constexpr size_t WS_WE3H   = WS_WE1H + (size_t)NEXP * FDIM * HDIM * 2;
static constexpr size_t WS_WE2H   = WS_WE3H + (size_t)NEXP * FDIM * HDIM * 2;
static constexpr size_t WS_H1S    = WS_WE2H + (size_t)NEXP * HDIM * FDIM * 2; // f16 [TDIM][FDIM]
static constexpr size_t WS_H1R    = WS_H1S + (size_t)TDIM * FDIM * 2;   // f16 [NSLOT][FDIM]
static constexpr size_t WS_RB     = WS_H1R + (size_t)NSLOT * FDIM * 2;  // f16 [NSLOT][HDIM]
static constexpr size_t WS_END    = WS_RB + (size_t)NSLOT * HDIM * 2;

// ---------------- small kernels ----------------

__global__ void zero_meta_kernel(int* __restrict__ counts) {
  if (threadIdx.x < 32) counts[threadIdx.x] = 0;
}

// fp32 -> f16 for 3 equal-size tensors (blockIdx.y selects), 8 elems/thread
__global__ void cvt3_kernel(const float* __restrict__ s0, const float* __restrict__ s1,
                            const float* __restrict__ s2, _Float16* __restrict__ d0,
                            _Float16* __restrict__ d1, _Float16* __restrict__ d2) {
  const float* s;
  _Float16* d;
  if (blockIdx.y == 0)      { s = s0; d = d0; }
  else if (blockIdx.y == 1) { s = s1; d = d1; }
  else                      { s = s2; d = d2; }
  size_t i = ((size_t)blockIdx.x * 256 + threadIdx.x) * 8;
  float4 a = *(const float4*)(s + i);
  float4 b = *(const float4*)(s + i + 4);
  half8 h;
  h[0] = (_Float16)a.x; h[1] = (_Float16)a.y; h[2] = (_Float16)a.z; h[3] = (_Float16)a.w;
  h[4] = (_Float16)b.x; h[5] = (_Float16)b.y; h[6] = (_Float16)b.z; h[7] = (_Float16)b.w;
  *(half8*)(d + i) = h;
}

// one wave per token: fp32 routing (discrete decisions must match reference).
// Also emits the f16 copy of x (row is already in registers) -> saves a cvt pass.
__global__ void gate_kernel(const float* __restrict__ x, const float* __restrict__ gw,
                            const float* __restrict__ bias, _Float16* __restrict__ xb,
                            int* __restrict__ toke, float* __restrict__ tokg,
                            int* __restrict__ counts) {
  const int wid  = blockIdx.x * 4 + (threadIdx.x >> 6);
  const int lane = threadIdx.x & 63;
  const float4* xv = (const float4*)(x + (size_t)wid * HDIM);
  const float4* gv = (const float4*)gw;
  _Float16* xrow = xb + (size_t)wid * HDIM;
  float acc[NEXP];
#pragma unroll
  for (int e = 0; e < NEXP; ++e) acc[e] = 0.f;
#pragma unroll
  for (int i = 0; i < 8; ++i) {
    float4 xq = xv[lane + 64 * i];
    half4 hq;
    hq[0] = (_Float16)xq.x; hq[1] = (_Float16)xq.y;
    hq[2] = (_Float16)xq.z; hq[3] = (_Float16)xq.w;
    *(half4*)(xrow + 4 * (lane + 64 * i)) = hq;
#pragma unroll
    for (int e = 0; e < NEXP; ++e) {
      float4 gq = gv[e * 512 + lane + 64 * i];
      acc[e] += xq.x * gq.x + xq.y * gq.y + xq.z * gq.z + xq.w * gq.w;
    }
  }
#pragma unroll
  for (int e = 0; e < NEXP; ++e) {
    float v = acc[e];
    for (int off = 32; off; off >>= 1) v += __shfl_xor(v, off);
    acc[e] = v;
  }
  if (lane == 0) {
    float s[NEXP], r[NEXP];
#pragma unroll
    for (int e = 0; e < NEXP; ++e) {
      s[e] = 1.f / (1.f + __expf(-acc[e]));
      r[e] = s[e] + bias[e];
    }
    int e0 = 0;
#pragma unroll
    for (int e = 1; e < NEXP; ++e) if (r[e] > r[e0]) e0 = e;
    int e1 = -1;
#pragma unroll
    for (int e = 0; e < NEXP; ++e) if (e != e0 && (e1 < 0 || r[e] > r[e1])) e1 = e;
    float g0 = s[e0], g1 = s[e1];
    float inv = 1.f / (g0 + g1);
    toke[wid * 2]     = e0;
    toke[wid * 2 + 1] = e1;
    tokg[wid * 2]     = g0 * inv;
    tokg[wid * 2 + 1] = g1 * inv;
    atomicAdd(&counts[e0], 1);
    atomicAdd(&counts[e1], 1);
  }
}

__global__ void offsets_kernel(const int* __restrict__ counts, int* __restrict__ offs) {
  if (threadIdx.x == 0) {
    int o = 0;
    for (int e = 0; e < NEXP; ++e) { offs[e] = o; o += counts[e]; }
  }
}

// also records token->slot map (tokslot) for the atomic-free merge
__global__ void scatter_kernel(const int* __restrict__ toke, const float* __restrict__ tokg,
                               const int* __restrict__ offs, int* __restrict__ fill,
                               int* __restrict__ slott, float* __restrict__ slotg,
                               int* __restrict__ tokslot) {
  int t = blockIdx.x * 256 + threadIdx.x;
#pragma unroll
  for (int j = 0; j < 2; ++j) {
    int e = toke[t * 2 + j];
    float g = tokg[t * 2 + j];
    int p = offs[e] + atomicAdd(&fill[e], 1);
    slott[p] = t;
    slotg[p] = g;
    tokslot[t * 2 + j] = p;
  }
}

// ---------------- GEMM kernels ----------------
// 128x128 tile, BK=32, double-buffered LDS, 256 thr (4 waves, 2x2 of 64x64),
// MFMA 16x16x32 f16. R9 schedule (measured best): stage(t+1) at TOP of
// iteration (overlaps MFMA), single __syncthreads per K-step. Hand-scheduled
// counted-vmcnt variants regressed twice (R8: 3 barriers; R11: 72KB LDS cut
// residency) -- do not reintroduce without the full 8-phase interleave.
// SPLIT (this round): up1 computes h1 = A@W1^T only; up3 computes
// silu(h1)*(A@W3^T). 2 LDS matrices -> 32KB/block (was 48KB) and acc halves
// -> static residency 3 -> 4-5 blocks/CU (TLP = the mechanism that works).
// T1 XCD group swizzle kept (FETCH -27%). Chunk-XOR LDS swizzle kept.
// bz: 0 = shared expert (dense), 1..8 = routed expert bz-1.

template <bool FIN>  // FIN=0: store h1. FIN=1: read h1, store silu(h1)*h3
__global__ __launch_bounds__(256) void up_gemm(
    const _Float16* __restrict__ xb,
    const _Float16* __restrict__ wsh, const _Float16* __restrict__ weh,
    _Float16* __restrict__ dsts, _Float16* __restrict__ dstr,
    const _Float16* __restrict__ h1s, const _Float16* __restrict__ h1r,
    const int* __restrict__ counts, const int* __restrict__ offs,
    const int* __restrict__ slott) {
  constexpr int GX = FDIM / 128;   // 11
  constexpr int GY = TDIM / 128;   // 32
  const int orig = blockIdx.x + GX * (blockIdx.y + GY * blockIdx.z);
  const int k8 = orig & 7, s = orig >> 3;
  const int g = k8 + 8 * (s / GX);
  const int lid = g * GX + (s % GX);
  const int bx = lid % GX;
  const int by = (lid / GX) % GY;
  const int bz = lid / (GX * GY);

  int cnt = TDIM, base = 0;
  const _Float16* __restrict__ W = wsh;
  _Float16* __restrict__ dst = dsts;
  const _Float16* __restrict__ h1 = h1s;
  bool gather = false;
  if (bz > 0) {
    const int e = bz - 1;
    cnt = counts[e];
    base = offs[e];
    if ((int)(by * 128) >= cnt) return;
    W = weh + (size_t)e * FDIM * HDIM;
    dst = dstr;
    h1 = h1r;
    gather = true;
  }
  const int m0 = by * 128, n0 = bx * 128;

  __shared__ _Float16 As[2][128 * BK];
  __shared__ _Float16 Bs[2][128 * BK];

  const int tid = threadIdx.x, lane = tid & 63, wv = tid >> 6;
  const int wm = wv >> 1, wn = wv & 1;
  const int lrow = lane & 15, quad = lane >> 4;

  const _Float16 *srcA[2], *srcB[2];
#pragma unroll
  for (int j = 0; j < 2; ++j) {
    const int rr = wv * 32 + j * 16 + (lane >> 2);
    const int gc = ((lane & 3) ^ ((rr >> 1) & 3)) * 8;  // pre-swizzled source chunk
    const int m = m0 + rr;
    int tok;
    if (gather) tok = slott[base + (m < cnt ? m : cnt - 1)];
    else tok = m;
    srcA[j] = xb + (size_t)tok * HDIM + gc;
    srcB[j] = W + (size_t)(n0 + rr) * HDIM + gc;
  }

  floatx4 acc[4][4] = {};
  const int cA = (quad ^ ((lrow >> 1) & 3)) * 8;  // swizzled read chunk (halfs)

  // prologue: stage tile 0
#pragma unroll
  for (int j = 0; j < 2; ++j) {
    const int lb = (wv * 32 + j * 16) * BK;
    g2l16(srcA[j], &As[0][lb]);
    g2l16(srcB[j], &Bs[0][lb]);
  }
  __syncthreads();

  for (int t = 0; t < HDIM / BK; ++t) {
    const int cur = t & 1;
    if (t + 1 < HDIM / BK) {  // issue next-tile loads first (hide under MFMA)
      const int k0 = (t + 1) * BK;
#pragma unroll
      for (int j = 0; j < 2; ++j) {
        const int lb = (wv * 32 + j * 16) * BK;
        g2l16(srcA[j] + k0, &As[cur ^ 1][lb]);
        g2l16(srcB[j] + k0, &Bs[cur ^ 1][lb]);
      }
    }
    half8 af[4], bf[4];
#pragma unroll
    for (int i = 0; i < 4; ++i)
      af[i] = *(const half8*)&As[cur][(wm * 64 + i * 16 + lrow) * BK + cA];
#pragma unroll
    for (int i = 0; i < 4; ++i)
      bf[i] = *(const half8*)&Bs[cur][(wn * 64 + i * 16 + lrow) * BK + cA];
#pragma unroll
    for (int ms = 0; ms < 4; ++ms)
#pragma unroll
      for (int ns = 0; ns < 4; ++ns)
        acc[ms][ns] = __builtin_amdgcn_mfma_f32_16x16x32_f16(af[ms], bf[ns], acc[ms][ns], 0, 0, 0);
    __syncthreads();
  }

  // epilogue (C/D layout: col=lane&15, row=quad*4+reg)
#pragma unroll
  for (int ms = 0; ms < 4; ++ms)
#pragma unroll
    for (int ns = 0; ns < 4; ++ns)
#pragma unroll
      for (int r = 0; r < 4; ++r) {
        const int rl = wm * 64 + ms * 16 + quad * 4 + r;
        const int f = n0 + wn * 64 + ns * 16 + lrow;
        const int m = m0 + rl;
        if (gather && m >= cnt) continue;
        const size_t row = gather ? (size_t)(base + m) : (size_t)m;
        float v = acc[ms][ns][r];
        if constexpr (FIN) {
          float h = (float)h1[row * FDIM + f];
          float a = h / (1.f + __expf(-h)) * v;
          dst[row * FDIM + f] = (_Float16)a;
        } else {
          dst[row * FDIM + f] = (_Float16)v;
        }
      }
}

// down: A (f16 act) @ W2^T. ATOMIC-FREE: shared (bz=0) plain-stores fp32 out;
// routed (bz>0) plain-stores f16 per-slot rows into rbuf (each slot row
// written by exactly one block column-range -> no conflicts). merge_kernel
// combines. (R7-R10 did 25M fp32 atomicAdds here -- suspected hidden sink.)
__global__ __launch_bounds__(256) void down_kernel(
    const _Float16* __restrict__ acts, const _Float16* __restrict__ actr,
    const _Float16* __restrict__ ws2h, const _Float16* __restrict__ we2h,
    float* __restrict__ out, _Float16* __restrict__ rbuf,
    const int* __restrict__ counts, const int* __restrict__ offs) {
  constexpr int GX = HDIM / 128;   // 16
  constexpr int GY = TDIM / 128;   // 32
  const int orig = blockIdx.x + GX * (blockIdx.y + GY * blockIdx.z);
  const int k8 = orig & 7, s = orig >> 3;
  const int g = k8 + 8 * (s / GX);
  const int lid = g * GX + (s % GX);
  const int bx = lid % GX;
  const int by = (lid / GX) % GY;
  const int bz = lid / (GX * GY);

  int cnt = TDIM, base = 0;
  const _Float16* __restrict__ A = acts;
  const _Float16* __restrict__ W = ws2h;
  bool gather = false;
  if (bz > 0) {
    const int e = bz - 1;
    cnt = counts[e];
    base = offs[e];
    if ((int)(by * 128) >= cnt) return;
    A = actr;
    W = we2h + (size_t)e * HDIM * FDIM;
    gather = true;
  }
  const int m0 = by * 128, n0 = bx * 128;

  __shared__ _Float16 As[2][128 * BK];
  __shared__ _Float16 Bs[2][128 * BK];

  const int tid = threadIdx.x, lane = tid & 63, wv = tid >> 6;
  const int wm = wv >> 1, wn = wv & 1;
  const int lrow = lane & 15, quad = lane >> 4;

  const _Float16 *srcA[2], *srcB[2];
#pragma unroll
  for (int j = 0; j < 2; ++j) {
    const int rr = wv * 32 + j * 16 + (lane >> 2);
    const int gc = ((lane & 3) ^ ((rr >> 1) & 3)) * 8;
    const int m = m0 + rr;
    int srow;
    if (gather) srow = base + (m < cnt ? m : cnt - 1);
    else srow = m;
    srcA[j] = A + (size_t)srow * FDIM + gc;
    srcB[j] = W + (size_t)(n0 + rr) * FDIM + gc;
  }

  floatx4 acc[4][4] = {};
  const int cA = (quad ^ ((lrow >> 1) & 3)) * 8;

#pragma unroll
  for (int j = 0; j < 2; ++j) {
    const int lb = (wv * 32 + j * 16) * BK;
    g2l16(srcA[j], &As[0][lb]);
    g2l16(srcB[j], &Bs[0][lb]);
  }
  __syncthreads();

  for (int t = 0; t < FDIM / BK; ++t) {
    const int cur = t & 1;
    if (t + 1 < FDIM / BK) {
      const int k0 = (t + 1) * BK;
#pragma unroll
      for (int j = 0; j < 2; ++j) {
        const int lb = (wv * 32 + j * 16) * BK;
        g2l16(srcA[j] + k0, &As[cur ^ 1][lb]);
        g2l16(srcB[j] + k0, &Bs[cur ^ 1][lb]);
      }
    }
    half8 af[4], bf[4];
#pragma unroll
    for (int i = 0; i < 4; ++i)
      af[i] = *(const half8*)&As[cur][(wm * 64 + i * 16 + lrow) * BK + cA];
#pragma unroll
    for (int i = 0; i < 4; ++i)
      bf[i] = *(const half8*)&Bs[cur][(wn * 64 + i * 16 + lrow) * BK + cA];
#pragma unroll
    for (int ms = 0; ms < 4; ++ms)
#pragma unroll
      for (int ns = 0; ns < 4; ++ns)
        acc[ms][ns] = __builtin_amdgcn_mfma_f32_16x16x32_f16(af[ms], bf[ns], acc[ms][ns], 0, 0, 0);
    __syncthreads();
  }

#pragma unroll
  for (int ms = 0; ms < 4; ++ms)
#pragma unroll
    for (int ns = 0; ns < 4; ++ns)
#pragma unroll
      for (int r = 0; r < 4; ++r) {
        float v = acc[ms][ns][r];
        const int rl = wm * 64 + ms * 16 + quad * 4 + r;
        const int h = n0 + wn * 64 + ns * 16 + lrow;
        const int m = m0 + rl;
        if (gather) {
          if (m < cnt) rbuf[(size_t)(base + m) * HDIM + h] = (_Float16)v;
        } else {
          out[(size_t)m * HDIM + h] = v;
        }
      }
}

// out[t] += g0*rbuf[p0] + g1*rbuf[p1]; one block per token, 8 h per thread
__global__ void merge_kernel(float* __restrict__ out, const _Float16* __restrict__ rbuf,
                             const int* __restrict__ tokslot, const float* __restrict__ tokg) {
  const int t = blockIdx.x;
  const int hc = threadIdx.x * 8;
  const int p0 = tokslot[t * 2], p1 = tokslot[t * 2 + 1];
  const float g0 = tokg[t * 2], g1 = tokg[t * 2 + 1];
  half8 r0 = *(const half8*)(rbuf + (size_t)p0 * HDIM + hc);
  half8 r1 = *(const half8*)(rbuf + (size_t)p1 * HDIM + hc);
  float* o = out + (size_t)t * HDIM + hc;
  float4 a = *(float4*)o;
  float4 b = *(float4*)(o + 4);
  a.x += g0 * (float)r0[0] + g1 * (float)r1[0];
  a.y += g0 * (float)r0[1] + g1 * (float)r1[1];
  a.z += g0 * (float)r0[2] + g1 * (float)r1[2];
  a.w += g0 * (float)r0[3] + g1 * (float)r1[3];
  b.x += g0 * (float)r0[4] + g1 * (float)r1[4];
  b.y += g0 * (float)r0[5] + g1 * (float)r1[5];
  b.z += g0 * (float)r0[6] + g1 * (float)r1[6];
  b.w += g0 * (float)r0[7] + g1 * (float)r1[7];
  *(float4*)o = a;
  *(float4*)(o + 4) = b;
}

// ---------------- launcher ----------------

extern "C" void kernel_launch(void* const* d_in, const int* in_sizes, int n_in,
                              void* d_out, int out_size, void* d_ws, size_t ws_size,
                              hipStream_t stream) {
  const float* x    = (const float*)d_in[0];
  const float* gw   = (const float*)d_in[1];
  const float* bias = (const float*)d_in[2];
  const float* ws1  = (const float*)d_in[3];
  const float* ws2  = (const float*)d_in[4];
  const float* ws3  = (const float*)d_in[5];
  const float* we1  = (const float*)d_in[6];
  const float* we2  = (const float*)d_in[7];
  const float* we3  = (const float*)d_in[8];
  float* out = (float*)d_out;

  char* ws = (char*)d_ws;
  _Float16* xb   = (_Float16*)(ws + WS_XB);
  _Float16* acts = (_Float16*)(ws + WS_ACT_S);
  _Float16* actr = (_Float16*)(ws + WS_ACT_R);
  int*   toke  = (int*)(ws + WS_TOKE);
  float* tokg  = (float*)(ws + WS_TOKG);
  int*   slott = (int*)(ws + WS_SLOTT);
  float* slotg = (float*)(ws + WS_SLOTG);
  int*   toks  = (int*)(ws + WS_TOKS);
  int* counts  = (int*)(ws + WS_COUNTS);
  int* fill    = (int*)(ws + WS_FILL);
  int* offs    = (int*)(ws + WS_OFFS);
  _Float16* ws1h = (_Float16*)(ws + WS_WS1H);
  _Float16* ws3h = (_Float16*)(ws + WS_WS3H);
  _Float16* ws2h = (_Float16*)(ws + WS_WS2H);
  _Float16* we1h = (_Float16*)(ws + WS_WE1H);
  _Float16* we3h = (_Float16*)(ws + WS_WE3H);
  _Float16* we2h = (_Float16*)(ws + WS_WE2H);
  _Float16* h1s  = (_Float16*)(ws + WS_H1S);
  _Float16* h1r  = (_Float16*)(ws + WS_H1R);
  _Float16* rbuf = (_Float16*)(ws + WS_RB);

  hipLaunchKernelGGL(zero_meta_kernel, dim3(1), dim3(64), 0, stream, counts);
  hipLaunchKernelGGL(gate_kernel, dim3(1024), dim3(256), 0, stream, x, gw, bias, xb, toke, tokg, counts);
  hipLaunchKernelGGL(offsets_kernel, dim3(1), dim3(64), 0, stream, counts, offs);
  hipLaunchKernelGGL(scatter_kernel, dim3(16), dim3(256), 0, stream, toke, tokg, offs, fill, slott, slotg, toks);

  constexpr int GS = (FDIM * HDIM) / 2048;           // 1408
  constexpr int GR = (NEXP * FDIM * HDIM) / 2048;    // 11264
  hipLaunchKernelGGL(cvt3_kernel, dim3(GS, 3), dim3(256), 0, stream, ws1, ws3, ws2, ws1h, ws3h, ws2h);
  hipLaunchKernelGGL(cvt3_kernel, dim3(GR, 3), dim3(256), 0, stream, we1, we3, we2, we1h, we3h, we2h);

  // z = 0: shared expert (dense); z = 1..8: routed expert z-1
  hipLaunchKernelGGL((up_gemm<false>), dim3(FDIM / 128, TDIM / 128, NEXP + 1), dim3(256), 0, stream,
                     xb, ws1h, we1h, h1s, h1r, nullptr, nullptr, counts, offs, slott);
  hipLaunchKernelGGL((up_gemm<true>), dim3(FDIM / 128, TDIM / 128, NEXP + 1), dim3(256), 0, stream,
                     xb, ws3h, we3h, acts, actr, h1s, h1r, counts, offs, slott);
  hipLaunchKernelGGL(down_kernel, dim3(HDIM / 128, TDIM / 128, NEXP + 1), dim3(256), 0, stream,
                     acts, actr, ws2h, we2h, out, rbuf, counts, offs);
  hipLaunchKernelGGL(merge_kernel, dim3(TDIM), dim3(256), 0, stream, out, rbuf, toks, tokg);
}